// Round 1
// baseline (1903.931 us; speedup 1.0000x reference)
//
#include <hip/hip_runtime.h>
#include <hip/hip_bf16.h>
#include <math.h>

// Problem constants
#define D_MODEL 256
#define DEPTH 2
#define D_INNER 512
#define D_STATE 16
#define D_CONV 4
#define DT_RANK 16
#define BATCH 2
#define SEQLEN 2048
#define MROWS (BATCH * SEQLEN)   // 4096

// ---------------------------------------------------------------------------
// LayerNorm: one block (256 threads) per row of 256 elements.
// ---------------------------------------------------------------------------
__global__ __launch_bounds__(256) void ln_kernel(
    const float* __restrict__ x, const float* __restrict__ w,
    const float* __restrict__ b, float* __restrict__ h)
{
    int row = blockIdx.x;
    int t = threadIdx.x;
    float v = x[(size_t)row * D_MODEL + t];
    float s = v, sq = v * v;
    #pragma unroll
    for (int off = 32; off > 0; off >>= 1) {
        s  += __shfl_xor(s, off);
        sq += __shfl_xor(sq, off);
    }
    __shared__ float ss[4], ssq[4];
    int wv = t >> 6;
    if ((t & 63) == 0) { ss[wv] = s; ssq[wv] = sq; }
    __syncthreads();
    s  = ss[0] + ss[1] + ss[2] + ss[3];
    sq = ssq[0] + ssq[1] + ssq[2] + ssq[3];
    float mu  = s * (1.0f / D_MODEL);
    float var = sq * (1.0f / D_MODEL) - mu * mu;
    float r = rsqrtf(var + 1e-5f);
    h[(size_t)row * D_MODEL + t] = (v - mu) * r * w[t] + b[t];
}

// ---------------------------------------------------------------------------
// C = A(MxK) * W(NxK)^T  (+ optional residual), f32, LDS-tiled 64x64x16,
// 256 threads, 4x4 microtile per thread.
// ---------------------------------------------------------------------------
__global__ __launch_bounds__(256) void gemm_nt(
    const float* __restrict__ A, const float* __restrict__ W,
    const float* __restrict__ resid, float* __restrict__ C,
    int M, int N, int K)
{
    const int BM = 64, BN = 64, BK = 16;
    __shared__ float As[BK][BM + 4];   // +4 pad: 2-way conflicts only (free)
    __shared__ float Ws[BK][BN + 4];
    int bm = blockIdx.y * BM;
    int bn = blockIdx.x * BN;
    int t  = threadIdx.x;
    int tm = (t >> 4) << 2;            // 0..60
    int tn = (t & 15) << 2;            // 0..60
    int lr = t >> 2;                   // 0..63 tile row for staging
    int lk = (t & 3) << 2;             // 0,4,8,12 k offset for staging
    const float* Ap = A + (size_t)(bm + lr) * K + lk;
    const float* Wp = W + (size_t)(bn + lr) * K + lk;
    float acc[4][4] = {};
    for (int k0 = 0; k0 < K; k0 += BK) {
        float4 av = *(const float4*)(Ap + k0);
        float4 wv = *(const float4*)(Wp + k0);
        __syncthreads();               // previous iter's reads complete
        As[lk + 0][lr] = av.x; As[lk + 1][lr] = av.y;
        As[lk + 2][lr] = av.z; As[lk + 3][lr] = av.w;
        Ws[lk + 0][lr] = wv.x; Ws[lk + 1][lr] = wv.y;
        Ws[lk + 2][lr] = wv.z; Ws[lk + 3][lr] = wv.w;
        __syncthreads();
        #pragma unroll
        for (int k = 0; k < BK; k++) {
            float4 a4 = *(const float4*)&As[k][tm];
            float4 w4 = *(const float4*)&Ws[k][tn];
            float ar[4] = {a4.x, a4.y, a4.z, a4.w};
            float wr[4] = {w4.x, w4.y, w4.z, w4.w};
            #pragma unroll
            for (int i = 0; i < 4; i++)
                #pragma unroll
                for (int j = 0; j < 4; j++)
                    acc[i][j] = fmaf(ar[i], wr[j], acc[i][j]);
        }
    }
    #pragma unroll
    for (int i = 0; i < 4; i++) {
        size_t off = (size_t)(bm + tm + i) * N + bn + tn;
        float4 o;
        if (resid) {
            float4 r = *(const float4*)(resid + off);
            o.x = r.x + acc[i][0]; o.y = r.y + acc[i][1];
            o.z = r.z + acc[i][2]; o.w = r.w + acc[i][3];
        } else {
            o.x = acc[i][0]; o.y = acc[i][1]; o.z = acc[i][2]; o.w = acc[i][3];
        }
        *(float4*)(C + off) = o;
    }
}

// ---------------------------------------------------------------------------
// Causal depthwise conv (k=4) + bias + SiLU.  xi = first half of xz rows.
// One block per (b,l) row; threads cover d (2 per thread).
// ---------------------------------------------------------------------------
__global__ __launch_bounds__(256) void conv_kernel(
    const float* __restrict__ xz, const float* __restrict__ cw,
    const float* __restrict__ cb, float* __restrict__ xc)
{
    int row = blockIdx.x;                  // b*SEQLEN + l
    int l = row & (SEQLEN - 1);
    int t = threadIdx.x;
    #pragma unroll
    for (int it = 0; it < 2; it++) {
        int d = t + it * 256;
        float s = cb[d];
        #pragma unroll
        for (int k = 0; k < D_CONV; k++) {
            int ls = l - (D_CONV - 1) + k;
            if (ls >= 0)
                s = fmaf(cw[d * D_CONV + k],
                         xz[(size_t)(row - (D_CONV - 1) + k) * (2 * D_INNER) + d], s);
        }
        xc[(size_t)row * D_INNER + d] = s / (1.0f + __expf(-s));
    }
}

// ---------------------------------------------------------------------------
// dbl = xc(row,512) @ xpw(48,512)^T.  One wave per row, lanes 0..47 active.
// ---------------------------------------------------------------------------
__global__ __launch_bounds__(256) void xproj_kernel(
    const float* __restrict__ xc, const float* __restrict__ xpw,
    float* __restrict__ dbl)
{
    int wv = threadIdx.x >> 6;
    int lane = threadIdx.x & 63;
    int row = blockIdx.x * 4 + wv;
    if (lane < 48) {
        const float* xr = xc + (size_t)row * D_INNER;
        const float* wr = xpw + (size_t)lane * D_INNER;
        float s = 0.f;
        for (int k = 0; k < D_INNER; k += 4) {
            float4 xv = *(const float4*)(xr + k);
            float4 wvv = *(const float4*)(wr + k);
            s = fmaf(xv.x, wvv.x, s); s = fmaf(xv.y, wvv.y, s);
            s = fmaf(xv.z, wvv.z, s); s = fmaf(xv.w, wvv.w, s);
        }
        dbl[(size_t)row * 48 + lane] = s;
    }
}

// ---------------------------------------------------------------------------
// delta = softplus(dt(row,16) @ dpw(512,16)^T + dpb).  Block per row.
// ---------------------------------------------------------------------------
__global__ __launch_bounds__(256) void delta_kernel(
    const float* __restrict__ dbl, const float* __restrict__ dpw,
    const float* __restrict__ dpb, float* __restrict__ delta)
{
    int row = blockIdx.x;
    int t = threadIdx.x;
    __shared__ float dts[DT_RANK];
    if (t < DT_RANK) dts[t] = dbl[(size_t)row * 48 + t];
    __syncthreads();
    #pragma unroll
    for (int it = 0; it < 2; it++) {
        int d = t + it * 256;
        const float* wr = dpw + (size_t)d * DT_RANK;
        float s = dpb[d];
        #pragma unroll
        for (int r = 0; r < DT_RANK; r++) s = fmaf(dts[r], wr[r], s);
        float sp = (s > 20.f) ? s : log1pf(__expf(s));
        delta[(size_t)row * D_INNER + d] = sp;
    }
}

// ---------------------------------------------------------------------------
// Selective scan, fused with skip (xc*D) and SiLU(z) gate -> yy.
// Thread = (channel d, state n). Block = 16 channels x 16 states.
// Register double-buffered 4-step prefetch to hide load latency.
// ---------------------------------------------------------------------------
#define SCAN_LOAD(DL, XV, BN, CN, LB)                                \
    {                                                                \
        _Pragma("unroll")                                            \
        for (int j = 0; j < 4; j++) {                                \
            size_t row = base + (LB) + j;                            \
            DL[j] = delta[row * D_INNER + d];                        \
            XV[j] = xc[row * D_INNER + d];                           \
            BN[j] = dbl[row * 48 + DT_RANK + n];                     \
            CN[j] = dbl[row * 48 + DT_RANK + D_STATE + n];           \
        }                                                            \
    }

#define SCAN_STEP(DL, XV, BN, CN, LB)                                \
    {                                                                \
        float res[4];                                                \
        _Pragma("unroll")                                            \
        for (int j = 0; j < 4; j++) {                                \
            float dA = __expf(DL[j] * a);                            \
            h = fmaf(dA, h, DL[j] * BN[j] * XV[j]);                  \
            float p = h * CN[j];                                     \
            p += __shfl_xor(p, 8, 16);                               \
            p += __shfl_xor(p, 4, 16);                               \
            p += __shfl_xor(p, 2, 16);                               \
            p += __shfl_xor(p, 1, 16);                               \
            res[j] = p;                                              \
        }                                                            \
        if (n == 0) {                                                \
            _Pragma("unroll")                                        \
            for (int j = 0; j < 4; j++) {                            \
                size_t row = base + (LB) + j;                        \
                float z = xz[row * (2 * D_INNER) + D_INNER + d];     \
                float sz = z / (1.0f + __expf(-z));                  \
                yy[row * D_INNER + d] = (res[j] + XV[j] * Dd) * sz;  \
            }                                                        \
        }                                                            \
    }

__global__ __launch_bounds__(256) void scan_kernel(
    const float* __restrict__ delta, const float* __restrict__ xc,
    const float* __restrict__ dbl, const float* __restrict__ xz,
    const float* __restrict__ A_log, const float* __restrict__ Dp,
    float* __restrict__ yy)
{
    int b  = blockIdx.x >> 5;              // 32 blocks per batch
    int d0 = (blockIdx.x & 31) << 4;
    int t = threadIdx.x;
    int c = t >> 4, n = t & 15;
    int d = d0 + c;
    float a  = -__expf(A_log[(size_t)d * D_STATE + n]);
    float Dd = Dp[d];
    float h = 0.f;
    size_t base = (size_t)b * SEQLEN;

    float dl0[4], xv0[4], bn0[4], cn0[4];
    float dl1[4], xv1[4], bn1[4], cn1[4];
    SCAN_LOAD(dl0, xv0, bn0, cn0, 0);
    for (int l = 0; l < SEQLEN; l += 8) {
        SCAN_LOAD(dl1, xv1, bn1, cn1, l + 4);
        SCAN_STEP(dl0, xv0, bn0, cn0, l);
        if (l + 8 < SEQLEN) SCAN_LOAD(dl0, xv0, bn0, cn0, l + 8);
        SCAN_STEP(dl1, xv1, bn1, cn1, l + 4);
    }
}

// ---------------------------------------------------------------------------
// Launch
// ---------------------------------------------------------------------------
extern "C" void kernel_launch(void* const* d_in, const int* in_sizes, int n_in,
                              void* d_out, int out_size, void* d_ws, size_t ws_size,
                              hipStream_t stream)
{
    const float* x    = (const float*)d_in[0];
    const float* lnw  = (const float*)d_in[1];
    const float* lnb  = (const float*)d_in[2];
    const float* ipw  = (const float*)d_in[3];
    const float* cw   = (const float*)d_in[4];
    const float* cb   = (const float*)d_in[5];
    const float* xpw  = (const float*)d_in[6];
    const float* dpw  = (const float*)d_in[7];
    const float* dpb  = (const float*)d_in[8];
    const float* alog = (const float*)d_in[9];
    const float* dpar = (const float*)d_in[10];
    const float* opw  = (const float*)d_in[11];
    float* out = (float*)d_out;

    float* ws = (float*)d_ws;
    float* xbuf = ws;                        // 4096*256
    float* hbuf = xbuf + (size_t)MROWS * D_MODEL;
    float* xzb  = hbuf + (size_t)MROWS * D_MODEL;          // 4096*1024
    float* xcb  = xzb  + (size_t)MROWS * 2 * D_INNER;      // 4096*512
    float* dblb = xcb  + (size_t)MROWS * D_INNER;          // 4096*48
    float* delb = dblb + (size_t)MROWS * 48;               // 4096*512
    float* yyb  = delb + (size_t)MROWS * D_INNER;          // 4096*512

    for (int lyr = 0; lyr < DEPTH; lyr++) {
        const float* xin = (lyr == 0) ? x : xbuf;
        float* xout = (lyr == DEPTH - 1) ? out : xbuf;

        ln_kernel<<<MROWS, 256, 0, stream>>>(
            xin, lnw + lyr * D_MODEL, lnb + lyr * D_MODEL, hbuf);

        gemm_nt<<<dim3((2 * D_INNER) / 64, MROWS / 64), 256, 0, stream>>>(
            hbuf, ipw + (size_t)lyr * 2 * D_INNER * D_MODEL, nullptr, xzb,
            MROWS, 2 * D_INNER, D_MODEL);

        conv_kernel<<<MROWS, 256, 0, stream>>>(
            xzb, cw + (size_t)lyr * D_INNER * D_CONV, cb + lyr * D_INNER, xcb);

        xproj_kernel<<<MROWS / 4, 256, 0, stream>>>(
            xcb, xpw + (size_t)lyr * 48 * D_INNER, dblb);

        delta_kernel<<<MROWS, 256, 0, stream>>>(
            dblb, dpw + (size_t)lyr * D_INNER * DT_RANK, dpb + lyr * D_INNER, delb);

        scan_kernel<<<64, 256, 0, stream>>>(
            delb, xcb, dblb, xzb,
            alog + (size_t)lyr * D_INNER * D_STATE, dpar + lyr * D_INNER, yyb);

        gemm_nt<<<dim3(D_MODEL / 64, MROWS / 64), 256, 0, stream>>>(
            yyb, opw + (size_t)lyr * D_MODEL * D_INNER, xin, xout,
            MROWS, D_MODEL, D_INNER);
    }
}

// Round 2
// 658.655 us; speedup vs baseline: 2.8906x; 2.8906x over previous
//
#include <hip/hip_runtime.h>
#include <hip/hip_bf16.h>
#include <math.h>

// Problem constants
#define D_MODEL 256
#define DEPTH 2
#define D_INNER 512
#define D_STATE 16
#define D_CONV 4
#define DT_RANK 16
#define BATCH 2
#define SEQLEN 2048
#define MROWS (BATCH * SEQLEN)   // 4096

// ---------------------------------------------------------------------------
// LayerNorm: one block (256 threads) per row of 256 elements.
// ---------------------------------------------------------------------------
__global__ __launch_bounds__(256) void ln_kernel(
    const float* __restrict__ x, const float* __restrict__ w,
    const float* __restrict__ b, float* __restrict__ h)
{
    int row = blockIdx.x;
    int t = threadIdx.x;
    float v = x[(size_t)row * D_MODEL + t];
    float s = v, sq = v * v;
    #pragma unroll
    for (int off = 32; off > 0; off >>= 1) {
        s  += __shfl_xor(s, off);
        sq += __shfl_xor(sq, off);
    }
    __shared__ float ss[4], ssq[4];
    int wv = t >> 6;
    if ((t & 63) == 0) { ss[wv] = s; ssq[wv] = sq; }
    __syncthreads();
    s  = ss[0] + ss[1] + ss[2] + ss[3];
    sq = ssq[0] + ssq[1] + ssq[2] + ssq[3];
    float mu  = s * (1.0f / D_MODEL);
    float var = sq * (1.0f / D_MODEL) - mu * mu;
    float r = rsqrtf(var + 1e-5f);
    h[(size_t)row * D_MODEL + t] = (v - mu) * r * w[t] + b[t];
}

// ---------------------------------------------------------------------------
// C = A(MxK) * W(NxK)^T  (+ optional residual), f32, LDS-tiled 64x64x16,
// 256 threads, 4x4 microtile per thread.
// ---------------------------------------------------------------------------
__global__ __launch_bounds__(256) void gemm_nt(
    const float* __restrict__ A, const float* __restrict__ W,
    const float* __restrict__ resid, float* __restrict__ C,
    int M, int N, int K)
{
    const int BM = 64, BN = 64, BK = 16;
    __shared__ float As[BK][BM + 4];   // +4 pad: 2-way conflicts only (free)
    __shared__ float Ws[BK][BN + 4];
    int bm = blockIdx.y * BM;
    int bn = blockIdx.x * BN;
    int t  = threadIdx.x;
    int tm = (t >> 4) << 2;            // 0..60
    int tn = (t & 15) << 2;            // 0..60
    int lr = t >> 2;                   // 0..63 tile row for staging
    int lk = (t & 3) << 2;             // 0,4,8,12 k offset for staging
    const float* Ap = A + (size_t)(bm + lr) * K + lk;
    const float* Wp = W + (size_t)(bn + lr) * K + lk;
    float acc[4][4] = {};
    for (int k0 = 0; k0 < K; k0 += BK) {
        float4 av = *(const float4*)(Ap + k0);
        float4 wv = *(const float4*)(Wp + k0);
        __syncthreads();               // previous iter's reads complete
        As[lk + 0][lr] = av.x; As[lk + 1][lr] = av.y;
        As[lk + 2][lr] = av.z; As[lk + 3][lr] = av.w;
        Ws[lk + 0][lr] = wv.x; Ws[lk + 1][lr] = wv.y;
        Ws[lk + 2][lr] = wv.z; Ws[lk + 3][lr] = wv.w;
        __syncthreads();
        #pragma unroll
        for (int k = 0; k < BK; k++) {
            float4 a4 = *(const float4*)&As[k][tm];
            float4 w4 = *(const float4*)&Ws[k][tn];
            float ar[4] = {a4.x, a4.y, a4.z, a4.w};
            float wr[4] = {w4.x, w4.y, w4.z, w4.w};
            #pragma unroll
            for (int i = 0; i < 4; i++)
                #pragma unroll
                for (int j = 0; j < 4; j++)
                    acc[i][j] = fmaf(ar[i], wr[j], acc[i][j]);
        }
    }
    #pragma unroll
    for (int i = 0; i < 4; i++) {
        size_t off = (size_t)(bm + tm + i) * N + bn + tn;
        float4 o;
        if (resid) {
            float4 r = *(const float4*)(resid + off);
            o.x = r.x + acc[i][0]; o.y = r.y + acc[i][1];
            o.z = r.z + acc[i][2]; o.w = r.w + acc[i][3];
        } else {
            o.x = acc[i][0]; o.y = acc[i][1]; o.z = acc[i][2]; o.w = acc[i][3];
        }
        *(float4*)(C + off) = o;
    }
}

// ---------------------------------------------------------------------------
// Causal depthwise conv (k=4) + bias + SiLU.  xi = first half of xz rows.
// One block per (b,l) row; threads cover d (2 per thread).
// ---------------------------------------------------------------------------
__global__ __launch_bounds__(256) void conv_kernel(
    const float* __restrict__ xz, const float* __restrict__ cw,
    const float* __restrict__ cb, float* __restrict__ xc)
{
    int row = blockIdx.x;                  // b*SEQLEN + l
    int l = row & (SEQLEN - 1);
    int t = threadIdx.x;
    #pragma unroll
    for (int it = 0; it < 2; it++) {
        int d = t + it * 256;
        float s = cb[d];
        #pragma unroll
        for (int k = 0; k < D_CONV; k++) {
            int ls = l - (D_CONV - 1) + k;
            if (ls >= 0)
                s = fmaf(cw[d * D_CONV + k],
                         xz[(size_t)(row - (D_CONV - 1) + k) * (2 * D_INNER) + d], s);
        }
        xc[(size_t)row * D_INNER + d] = s / (1.0f + __expf(-s));
    }
}

// ---------------------------------------------------------------------------
// dbl = xc(row,512) @ xpw(48,512)^T.  One wave per row, lanes 0..47 active.
// ---------------------------------------------------------------------------
__global__ __launch_bounds__(256) void xproj_kernel(
    const float* __restrict__ xc, const float* __restrict__ xpw,
    float* __restrict__ dbl)
{
    int wv = threadIdx.x >> 6;
    int lane = threadIdx.x & 63;
    int row = blockIdx.x * 4 + wv;
    if (lane < 48) {
        const float* xr = xc + (size_t)row * D_INNER;
        const float* wr = xpw + (size_t)lane * D_INNER;
        float s = 0.f;
        for (int k = 0; k < D_INNER; k += 4) {
            float4 xv = *(const float4*)(xr + k);
            float4 wvv = *(const float4*)(wr + k);
            s = fmaf(xv.x, wvv.x, s); s = fmaf(xv.y, wvv.y, s);
            s = fmaf(xv.z, wvv.z, s); s = fmaf(xv.w, wvv.w, s);
        }
        dbl[(size_t)row * 48 + lane] = s;
    }
}

// ---------------------------------------------------------------------------
// delta = softplus(dt(row,16) @ dpw(512,16)^T + dpb).  Block per row.
// ---------------------------------------------------------------------------
__global__ __launch_bounds__(256) void delta_kernel(
    const float* __restrict__ dbl, const float* __restrict__ dpw,
    const float* __restrict__ dpb, float* __restrict__ delta)
{
    int row = blockIdx.x;
    int t = threadIdx.x;
    __shared__ float dts[DT_RANK];
    if (t < DT_RANK) dts[t] = dbl[(size_t)row * 48 + t];
    __syncthreads();
    #pragma unroll
    for (int it = 0; it < 2; it++) {
        int d = t + it * 256;
        const float* wr = dpw + (size_t)d * DT_RANK;
        float s = dpb[d];
        #pragma unroll
        for (int r = 0; r < DT_RANK; r++) s = fmaf(dts[r], wr[r], s);
        float sp = (s > 20.f) ? s : log1pf(__expf(s));
        delta[(size_t)row * D_INNER + d] = sp;
    }
}

// ---------------------------------------------------------------------------
// Selective scan — chunked parallel (linear-recurrence decomposition).
// One block per (b, d). 256 threads = 16 chunks x 16 states.
// Phase 1: per-chunk scan from 0 -> summary (P = prod dA via log-domain,
//          S = h_end). Phase 2: 16-step serial scan over chunk summaries.
// Phase 3: rescan from true h_init, reduce over n, fused D-skip + SiLU gate.
// ---------------------------------------------------------------------------
#define LC (SEQLEN / 16)   // 128 rows per chunk

__global__ __launch_bounds__(256) void scan_kernel(
    const float* __restrict__ delta, const float* __restrict__ xc,
    const float* __restrict__ dbl, const float* __restrict__ xz,
    const float* __restrict__ A_log, const float* __restrict__ Dp,
    float* __restrict__ yy)
{
    int b = blockIdx.x >> 9;           // D_INNER == 512
    int d = blockIdx.x & 511;
    int t = threadIdx.x;
    int c = t >> 4, n = t & 15;        // chunk, state
    float a = -__expf(A_log[(size_t)d * D_STATE + n]);
    size_t base = (size_t)b * SEQLEN + (size_t)c * LC;

    __shared__ float Sarr[16][16];
    __shared__ float Parr[16][16];
    __shared__ float Hini[16][16];

    // Phase 1: chunk-local scan from h=0; accumulate sum(delta) for P.
    float h = 0.f, sd = 0.f;
    #pragma unroll 4
    for (int j = 0; j < LC; j++) {
        size_t row = base + j;
        float dl = delta[row * D_INNER + d];
        float bn = dbl[row * 48 + DT_RANK + n];
        float xv = xc[row * D_INNER + d];
        sd += dl;
        float dA = __expf(dl * a);
        h = fmaf(dA, h, dl * bn * xv);
    }
    Sarr[c][n] = h;
    Parr[c][n] = __expf(a * sd);
    __syncthreads();

    // Phase 2: exclusive scan over the 16 chunk summaries (per state n).
    if (t < 16) {
        float hi = 0.f;
        #pragma unroll
        for (int cc = 0; cc < 16; cc++) {
            Hini[cc][t] = hi;
            hi = fmaf(Parr[cc][t], hi, Sarr[cc][t]);
        }
    }
    __syncthreads();

    // Phase 3: rescan from true initial state, produce gated output.
    h = Hini[c][n];
    float Dd = Dp[d];
    #pragma unroll 4
    for (int j = 0; j < LC; j++) {
        size_t row = base + j;
        float dl = delta[row * D_INNER + d];
        float bn = dbl[row * 48 + DT_RANK + n];
        float cn = dbl[row * 48 + DT_RANK + D_STATE + n];
        float xv = xc[row * D_INNER + d];
        float dA = __expf(dl * a);
        h = fmaf(dA, h, dl * bn * xv);
        float p = h * cn;
        p += __shfl_xor(p, 8, 16);
        p += __shfl_xor(p, 4, 16);
        p += __shfl_xor(p, 2, 16);
        p += __shfl_xor(p, 1, 16);
        if (n == 0) {
            float z = xz[row * (2 * D_INNER) + D_INNER + d];
            float sz = z / (1.0f + __expf(-z));
            yy[row * D_INNER + d] = (p + xv * Dd) * sz;
        }
    }
}

// ---------------------------------------------------------------------------
// Launch
// ---------------------------------------------------------------------------
extern "C" void kernel_launch(void* const* d_in, const int* in_sizes, int n_in,
                              void* d_out, int out_size, void* d_ws, size_t ws_size,
                              hipStream_t stream)
{
    const float* x    = (const float*)d_in[0];
    const float* lnw  = (const float*)d_in[1];
    const float* lnb  = (const float*)d_in[2];
    const float* ipw  = (const float*)d_in[3];
    const float* cw   = (const float*)d_in[4];
    const float* cb   = (const float*)d_in[5];
    const float* xpw  = (const float*)d_in[6];
    const float* dpw  = (const float*)d_in[7];
    const float* dpb  = (const float*)d_in[8];
    const float* alog = (const float*)d_in[9];
    const float* dpar = (const float*)d_in[10];
    const float* opw  = (const float*)d_in[11];
    float* out = (float*)d_out;

    float* ws = (float*)d_ws;
    float* xbuf = ws;                        // 4096*256
    float* hbuf = xbuf + (size_t)MROWS * D_MODEL;
    float* xzb  = hbuf + (size_t)MROWS * D_MODEL;          // 4096*1024
    float* xcb  = xzb  + (size_t)MROWS * 2 * D_INNER;      // 4096*512
    float* dblb = xcb  + (size_t)MROWS * D_INNER;          // 4096*48
    float* delb = dblb + (size_t)MROWS * 48;               // 4096*512
    float* yyb  = delb + (size_t)MROWS * D_INNER;          // 4096*512

    for (int lyr = 0; lyr < DEPTH; lyr++) {
        const float* xin = (lyr == 0) ? x : xbuf;
        float* xout = (lyr == DEPTH - 1) ? out : xbuf;

        ln_kernel<<<MROWS, 256, 0, stream>>>(
            xin, lnw + lyr * D_MODEL, lnb + lyr * D_MODEL, hbuf);

        gemm_nt<<<dim3((2 * D_INNER) / 64, MROWS / 64), 256, 0, stream>>>(
            hbuf, ipw + (size_t)lyr * 2 * D_INNER * D_MODEL, nullptr, xzb,
            MROWS, 2 * D_INNER, D_MODEL);

        conv_kernel<<<MROWS, 256, 0, stream>>>(
            xzb, cw + (size_t)lyr * D_INNER * D_CONV, cb + lyr * D_INNER, xcb);

        xproj_kernel<<<MROWS / 4, 256, 0, stream>>>(
            xcb, xpw + (size_t)lyr * 48 * D_INNER, dblb);

        delta_kernel<<<MROWS, 256, 0, stream>>>(
            dblb, dpw + (size_t)lyr * D_INNER * DT_RANK, dpb + lyr * D_INNER, delb);

        scan_kernel<<<BATCH * D_INNER, 256, 0, stream>>>(
            delb, xcb, dblb, xzb,
            alog + (size_t)lyr * D_INNER * D_STATE, dpar + lyr * D_INNER, yyb);

        gemm_nt<<<dim3(D_MODEL / 64, MROWS / 64), 256, 0, stream>>>(
            yyb, opw + (size_t)lyr * D_MODEL * D_INNER, xin, xout,
            MROWS, D_MODEL, D_INNER);
    }
}